// Round 9
// baseline (594.319 us; speedup 1.0000x reference)
//
#include <hip/hip_runtime.h>
#include <math.h>

#define HDIM 256
#define NHEADS 8
#define NEG 0.2f
#define STRIDE 768   // padded CSR row stride (max degree ~590)
#define SEG 4        // gather segments per node row

typedef float f32x4 __attribute__((ext_vector_type(4)));
typedef _Float16 f16x8 __attribute__((ext_vector_type(8)));
typedef __fp16 fp16v2 __attribute__((ext_vector_type(2)));

union H8 { f16x8 v8; fp16v2 v2[4]; _Float16 h[8]; };

#if __has_builtin(__builtin_amdgcn_fdot2)
#define FDOT2(a, b, c) __builtin_amdgcn_fdot2((a), (b), (c), false)
#else
__device__ __forceinline__ float FDOT2(fp16v2 a, fp16v2 b, float c) {
  return fmaf((float)a[1], (float)b[1], fmaf((float)a[0], (float)b[0], c));
}
#endif

// ---------------- zero scratch (rcnt + asum + dcol: 3072 ints) ---------------
__global__ __launch_bounds__(256) void zero_k(int* __restrict__ p) {
  p[blockIdx.x * 256 + threadIdx.x] = 0;
}

// ---------------- prep: CSR build + weight prep + rank-1 embmap --------------
__global__ __launch_bounds__(256) void prep_k(
    const int* __restrict__ ei, const float* __restrict__ ea, int E,
    const float* __restrict__ Wl, const float* __restrict__ Wr,
    const float* __restrict__ p1W, const float* __restrict__ W2,
    const float* __restrict__ embW, const float* __restrict__ embb,
    const float* __restrict__ bl, const float* __restrict__ br,
    int* __restrict__ rcnt, float* __restrict__ asum, int* __restrict__ dcol,
    float4* __restrict__ csr,
    unsigned short* __restrict__ Whall, unsigned short* __restrict__ W2h,
    float* __restrict__ ul, float* __restrict__ vl,
    float* __restrict__ ur, float* __restrict__ vr) {
  __shared__ __align__(16) char SMEM[14336];
  int wid = blockIdx.x;
  int WB = (E + 1023) >> 10;
  int t = threadIdx.x;

  if (wid < WB) {
    int*   lcnt = (int*)SMEM;
    float* ls0  = (float*)(SMEM + 2048);
    float* ls1  = (float*)(SMEM + 4096);
    float* ls2  = (float*)(SMEM + 6144);
    int*   lcol = (int*)(SMEM + 8192);
    int*   lbase= (int*)(SMEM + 12288);
    for (int n = t; n < 512; n += 256) {
      lcnt[n] = 0; ls0[n] = 0.f; ls1[n] = 0.f; ls2[n] = 0.f;
      lcol[n] = 0; lcol[512 + n] = 0;
    }
    __syncthreads();
    int e0 = wid << 10, e1 = min(E, e0 + 1024);
    int nd[4], ns[4], slot[4];
    float va0[4], va1[4], va2[4];
#pragma unroll
    for (int k = 0; k < 4; ++k) {
      int e = e0 + t + (k << 8);
      if (e < e1) {
        int src = ei[e], dst = ei[E + e];
        float a0 = ea[3*e], a1 = ea[3*e+1], a2 = ea[3*e+2];
        nd[k] = dst; ns[k] = src; va0[k] = a0; va1[k] = a1; va2[k] = a2;
        slot[k] = atomicAdd(&lcnt[dst], 1);
        atomicAdd(&ls0[dst], a0);
        atomicAdd(&ls1[dst], a1);
        atomicAdd(&ls2[dst], a2);
        int idx = 0; float best = a0;
        if (a1 > best) { best = a1; idx = 1; }
        if (a2 > best) { idx = 2; }
        if (idx) {
          int o = (idx - 1) << 9;
          atomicAdd(&lcol[o + src], 1);
          atomicAdd(&lcol[o + dst], 1);
        }
      } else {
        nd[k] = -1;
      }
    }
    __syncthreads();
    for (int n = t; n < 512; n += 256) {
      int c = lcnt[n];
      if (c) {
        lbase[n] = atomicAdd(&rcnt[n], c);
        atomicAdd(&asum[n],        ls0[n]);
        atomicAdd(&asum[512 + n],  ls1[n]);
        atomicAdd(&asum[1024 + n], ls2[n]);
      }
      int c0 = lcol[n], c1 = lcol[512 + n];
      if (c0) atomicAdd(&dcol[n], c0);
      if (c1) atomicAdd(&dcol[512 + n], c1);
    }
    __syncthreads();
#pragma unroll
    for (int k = 0; k < 4; ++k) {
      if (nd[k] >= 0) {
        int pos = nd[k]*STRIDE + lbase[nd[k]] + slot[k];
        csr[pos] = make_float4(va0[k], va1[k], va2[k], __int_as_float(ns[k]));
      }
    }
  } else if (wid < WB + 672) {
    int q = (wid - WB) * 256 + t;
    int base = q << 2;
    const float* src; unsigned short* d; int k, n, stride;
    if (base < 10*65536) {
      int s = base >> 16, r = base & 65535;
      int kj = r & 7, lane = (r >> 3) & 63, c = (r >> 9) & 7, nt = r >> 12;
      src = (s < 4) ? (Wl + (size_t)s*65536)
          : (s < 8) ? (Wr + (size_t)(s-4)*65536)
                    : (p1W + (size_t)(s-8)*65536);
      k = c*32 + (lane >> 4)*8 + kj;
      n = nt*16 + (lane & 15);
      d = Whall + base; stride = 256;
    } else {
      int off = base - 10*65536;
      int kj = off & 7, lane = (off >> 3) & 63, nt = (off >> 9) & 7, c = off >> 12;
      k = c*32 + (lane >> 4)*8 + kj;
      n = nt*16 + (lane & 15);
      src = W2; d = W2h + off; stride = 128;
    }
    union { fp16v2 v[2]; unsigned long long u; } uu;
    uu.v[0] = __builtin_amdgcn_cvt_pkrtz(src[(size_t)k*stride + n],
                                         src[(size_t)(k+1)*stride + n]);
    uu.v[1] = __builtin_amdgcn_cvt_pkrtz(src[(size_t)(k+2)*stride + n],
                                         src[(size_t)(k+3)*stride + n]);
    *(unsigned long long*)d = uu.u;
  } else {
    int q = wid - WB - 672;
    const float* W  = q ? Wr : Wl;
    const float* bb = q ? br : bl;
    float* u = q ? ur : ul;
    float* v = q ? vr : vl;
    float su = 0.f, sv = 0.f;
    for (int k = 0; k < 256; ++k) {
      float wv = W[(size_t)k*256 + t];
      su = fmaf(embW[k], wv, su);
      sv = fmaf(embb[k], wv, sv);
    }
    u[t] = su;
    v[t] = sv + bb[t];
  }
}

// ---------------- online-softmax edge step (packed f16 scoring) --------------
__device__ __forceinline__ void edge_step(float rx, float ry, float rz,
    f16x8 cur, f16x8 xr8, const union H8& w0u, const union H8& w1u,
    const union H8& w2u, const union H8& avu,
    float& mh, float& lh, float* acc) {
  _Float16 hx = (_Float16)rx, hy = (_Float16)ry, hz = (_Float16)rz;
  f16x8 s = cur + xr8;
  s = s + w0u.v8 * hx;
  s = s + w1u.v8 * hy;
  s = s + w2u.v8 * hz;
  union H8 m;
  m.v8 = __builtin_elementwise_max(s, s * (_Float16)NEG);
  float partial = FDOT2(m.v2[3], avu.v2[3],
                  FDOT2(m.v2[2], avu.v2[2],
                  FDOT2(m.v2[1], avu.v2[1],
                  FDOT2(m.v2[0], avu.v2[0], 0.f))));
  partial += __shfl_xor(partial, 1);
  partial += __shfl_xor(partial, 2);
  if (partial - mh > 8.f) {
    float sc = __expf(mh - partial);
    lh *= sc;
#pragma unroll
    for (int j = 0; j < 8; ++j) acc[j] *= sc;
    mh = partial;
  }
  float pw = __expf(partial - mh);
  lh += pw;
  union H8 cu; cu.v8 = cur;
#pragma unroll
  for (int j = 0; j < 8; ++j) acc[j] = fmaf(pw, (float)cu.h[j], acc[j]);
}

// ---------------- shared gather tail: merge 8 groups -> partials -------------
__device__ __forceinline__ void gat_tail(int nb, int t, float mh, float lh,
    float* acc, float* pm, float* pl, float* pacc,
    float* lacc, float* lm, float* llv) {
  int g = t >> 5, lane = t & 31, hd = lane >> 2, qd = lane & 3;
  int cb = hd*32 + qd*8;
#pragma unroll
  for (int j = 0; j < 8; ++j) lacc[g*HDIM + cb + j] = acc[j];
  if (qd == 0) { lm[g*NHEADS + hd] = mh; llv[g*NHEADS + hd] = lh; }
  __syncthreads();
  int c = t, hh = c >> 5;
  float M = -1e30f;
#pragma unroll
  for (int g2 = 0; g2 < 8; ++g2) M = fmaxf(M, lm[g2*NHEADS + hh]);
  float L = 0.f, o = 0.f;
#pragma unroll
  for (int g2 = 0; g2 < 8; ++g2) {
    float e2 = __expf(lm[g2*NHEADS + hh] - M);
    L = fmaf(llv[g2*NHEADS + hh], e2, L);
    o = fmaf(lacc[g2*HDIM + c], e2, o);
  }
  pacc[(size_t)nb*HDIM + c] = o;
  if ((c & 31) == 0) {
    pm[nb*NHEADS + hh] = M;
    pl[nb*NHEADS + hh] = L;
  }
}

// ---------------- gat0: layer-0 segmented gather (rank-1 on the fly) ---------
__global__ __launch_bounds__(256, 4) void gat0_k(
    const float* __restrict__ x,
    const float* __restrict__ ul, const float* __restrict__ vl,
    const float* __restrict__ ur, const float* __restrict__ vr,
    const float4* __restrict__ csr, const int* __restrict__ rcnt,
    const float* __restrict__ asum,
    const float* __restrict__ We, const float* __restrict__ att,
    float* __restrict__ pm, float* __restrict__ pl, float* __restrict__ pacc,
    int N) {
  __shared__ float lacc[8*HDIM];
  __shared__ float lm[8*NHEADS], llv[8*NHEADS];
  int nb = blockIdx.x;
  int n = nb >> 2, sgm = nb & (SEG - 1);
  int t = threadIdx.x;
  int g = t >> 5, lane = t & 31, hd = lane >> 2, qd = lane & 3;
  int cb = hd*32 + qd*8;

  union H8 w0u, w1u, w2u, avu;
#pragma unroll
  for (int p = 0; p < 4; ++p) {
    w0u.v2[p] = __builtin_amdgcn_cvt_pkrtz(We[cb+2*p],        We[cb+2*p+1]);
    w1u.v2[p] = __builtin_amdgcn_cvt_pkrtz(We[HDIM+cb+2*p],   We[HDIM+cb+2*p+1]);
    w2u.v2[p] = __builtin_amdgcn_cvt_pkrtz(We[2*HDIM+cb+2*p], We[2*HDIM+cb+2*p+1]);
    avu.v2[p] = __builtin_amdgcn_cvt_pkrtz(att[cb+2*p],       att[cb+2*p+1]);
  }
  float xv = x[n];
  float ul8[8], vl8[8];
#pragma unroll
  for (int j = 0; j < 8; ++j) { ul8[j] = ul[cb+j]; vl8[j] = vl[cb+j]; }
  union H8 xr8u;
#pragma unroll
  for (int p = 0; p < 4; ++p)
    xr8u.v2[p] = __builtin_amdgcn_cvt_pkrtz(
        fmaf(xv, ur[cb+2*p],   vr[cb+2*p]),
        fmaf(xv, ur[cb+2*p+1], vr[cb+2*p+1]));
  f16x8 xr8 = xr8u.v8;

  int cnt = rcnt[n];
  int base = n * STRIDE;
  int s0 = base + ((cnt * sgm) >> 2);
  int s1 = base + ((cnt * (sgm + 1)) >> 2);
  float mh = -1e30f, lh = 0.f;
  float acc[8] = {0.f,0.f,0.f,0.f,0.f,0.f,0.f,0.f};

  if (sgm == 0 && g == 0) {           // self-loop seed (mean edge_attr)
    union H8 xls;
#pragma unroll
    for (int p = 0; p < 4; ++p)
      xls.v2[p] = __builtin_amdgcn_cvt_pkrtz(
          fmaf(xv, ul8[2*p],   vl8[2*p]),
          fmaf(xv, ul8[2*p+1], vl8[2*p+1]));
    float inv = 1.f / fmaxf((float)cnt, 1.f);
    edge_step(asum[n]*inv, asum[512+n]*inv, asum[1024+n]*inv,
              xls.v8, xr8, w0u, w1u, w2u, avu, mh, lh, acc);
  }

  int idx = s0 + g;
  if (idx < s1) {
    int i1 = idx + 8, i2 = idx + 16;
    float4 rec  = csr[idx];
    float4 rec1 = csr[i1 < s1 ? i1 : base];
    float4 rec2 = csr[i2 < s1 ? i2 : base];
    float xs  = x[__float_as_int(rec.w)];
    float xs1 = x[__float_as_int(rec1.w)];
    while (idx < s1) {
      int i3 = i2 + 8;
      float4 rec3 = csr[i3 < s1 ? i3 : base];
      float xs2 = x[__float_as_int(rec2.w)];
      union H8 cur;
#pragma unroll
      for (int p = 0; p < 4; ++p)
        cur.v2[p] = __builtin_amdgcn_cvt_pkrtz(
            fmaf(xs, ul8[2*p],   vl8[2*p]),
            fmaf(xs, ul8[2*p+1], vl8[2*p+1]));
      edge_step(rec.x, rec.y, rec.z, cur.v8, xr8, w0u, w1u, w2u, avu,
                mh, lh, acc);
      rec = rec1; rec1 = rec2; rec2 = rec3;
      xs = xs1; xs1 = xs2;
      idx = i1; i1 = i2; i2 = i3;
    }
  }

  gat_tail(nb, t, mh, lh, acc, pm, pl, pacc, lacc, lm, llv);
}

// ---------------- gat: generic segmented gather (f16 xl table) ---------------
__global__ __launch_bounds__(256, 4) void gat_k(
    const unsigned short* __restrict__ xl_in,
    const unsigned short* __restrict__ xr_in,
    const float4* __restrict__ csr, const int* __restrict__ rcnt,
    const float* __restrict__ asum,
    const float* __restrict__ We, const float* __restrict__ att,
    float* __restrict__ pm, float* __restrict__ pl, float* __restrict__ pacc,
    int N) {
  __shared__ float lacc[8*HDIM];
  __shared__ float lm[8*NHEADS], llv[8*NHEADS];
  int nb = blockIdx.x;
  int n = nb >> 2, sgm = nb & (SEG - 1);
  int t = threadIdx.x;
  int g = t >> 5, lane = t & 31, hd = lane >> 2, qd = lane & 3;
  int cb = hd*32 + qd*8;

  union H8 w0u, w1u, w2u, avu;
#pragma unroll
  for (int p = 0; p < 4; ++p) {
    w0u.v2[p] = __builtin_amdgcn_cvt_pkrtz(We[cb+2*p],        We[cb+2*p+1]);
    w1u.v2[p] = __builtin_amdgcn_cvt_pkrtz(We[HDIM+cb+2*p],   We[HDIM+cb+2*p+1]);
    w2u.v2[p] = __builtin_amdgcn_cvt_pkrtz(We[2*HDIM+cb+2*p], We[2*HDIM+cb+2*p+1]);
    avu.v2[p] = __builtin_amdgcn_cvt_pkrtz(att[cb+2*p],       att[cb+2*p+1]);
  }
  f16x8 xr8 = *(const f16x8*)(xr_in + (size_t)n*HDIM + cb);

  int cnt = rcnt[n];
  int base = n * STRIDE;
  int s0 = base + ((cnt * sgm) >> 2);
  int s1 = base + ((cnt * (sgm + 1)) >> 2);
  float mh = -1e30f, lh = 0.f;
  float acc[8] = {0.f,0.f,0.f,0.f,0.f,0.f,0.f,0.f};

  if (sgm == 0 && g == 0) {           // self-loop seed
    f16x8 xls = *(const f16x8*)(xl_in + (size_t)n*HDIM + cb);
    float inv = 1.f / fmaxf((float)cnt, 1.f);
    edge_step(asum[n]*inv, asum[512+n]*inv, asum[1024+n]*inv,
              xls, xr8, w0u, w1u, w2u, avu, mh, lh, acc);
  }

  int idx = s0 + g;
  if (idx < s1) {
    int i1 = idx + 8, i2 = idx + 16;
    float4 rec  = csr[idx];
    float4 rec1 = csr[i1 < s1 ? i1 : base];
    float4 rec2 = csr[i2 < s1 ? i2 : base];
    union H8 cur, nxt, nx2;
    cur.v8 = *(const f16x8*)(xl_in + (size_t)__float_as_int(rec.w)*HDIM + cb);
    nxt.v8 = *(const f16x8*)(xl_in + (size_t)__float_as_int(rec1.w)*HDIM + cb);
    while (idx < s1) {
      int i3 = i2 + 8;
      float4 rec3 = csr[i3 < s1 ? i3 : base];
      nx2.v8 = *(const f16x8*)(xl_in +
                (size_t)__float_as_int(rec2.w)*HDIM + cb);
      edge_step(rec.x, rec.y, rec.z, cur.v8, xr8, w0u, w1u, w2u, avu,
                mh, lh, acc);
      rec = rec1; rec1 = rec2; rec2 = rec3;
      cur.v8 = nxt.v8; nxt.v8 = nx2.v8;
      idx = i1; i1 = i2; i2 = i3;
    }
  }

  gat_tail(nb, t, mh, lh, acc, pm, pl, pacc, lacc, lm, llv);
}

// ---------------- mrg: combine SEG partials + residual + LN + fused GEMM -----
__global__ __launch_bounds__(256, 4) void mrg_k(
    const float* __restrict__ pm, const float* __restrict__ pl,
    const float* __restrict__ pacc,
    const float* __restrict__ h_in,
    const float* __restrict__ x, const float* __restrict__ embW,
    const float* __restrict__ embb,
    const float* __restrict__ gbl, const float* __restrict__ lngl,
    const float* __restrict__ lnbl,
    const unsigned short* __restrict__ WhA, const unsigned short* __restrict__ WhB,
    const float* __restrict__ bA, const float* __restrict__ bB,
    float* __restrict__ h_out, unsigned short* __restrict__ xl_out,
    unsigned short* __restrict__ xr_out,
    const int* __restrict__ dcol, const float* __restrict__ coup,
    float* __restrict__ eout, int N) {
  __shared__ float rs1[4], rs2[4];
  __shared__ unsigned short h16[HDIM];
  int n = blockIdx.x, t = threadIdx.x;

  // Potts energy (layer-0 merge, block 0 only)
  if (eout && n == 0) {
    float e = 0.f;
    for (int id = t; id < N; id += 256) {
      float d1 = (float)dcol[id], d2 = (float)dcol[512 + id];
      e = fmaf(d1, d1, fmaf(d2, d2, e));
    }
#pragma unroll
    for (int off = 1; off < 64; off <<= 1) e += __shfl_xor(e, off);
    if ((t & 63) == 0) rs1[t >> 6] = e;
    __syncthreads();
    if (t == 0)
      eout[0] = coup[0] * (rs1[0] + rs1[1] + rs1[2] + rs1[3]) / (2.f * (float)N);
    __syncthreads();
  }

  int c = t, hh = c >> 5;
  float M = -1e30f;
#pragma unroll
  for (int s = 0; s < SEG; ++s) M = fmaxf(M, pm[(n*SEG + s)*NHEADS + hh]);
  float L = 0.f, o = 0.f;
#pragma unroll
  for (int s = 0; s < SEG; ++s) {
    float e2 = __expf(pm[(n*SEG + s)*NHEADS + hh] - M);
    L = fmaf(pl[(n*SEG + s)*NHEADS + hh], e2, L);
    o = fmaf(pacc[(size_t)(n*SEG + s)*HDIM + c], e2, o);
  }
  float hi = h_in ? h_in[(size_t)n*HDIM + c] : fmaf(x[n], embW[c], embb[c]);
  float val = o / L + gbl[c] + hi;

  // LayerNorm + relu
  float vs = val, vq = val * val;
#pragma unroll
  for (int off = 1; off < 64; off <<= 1) {
    vs += __shfl_xor(vs, off);
    vq += __shfl_xor(vq, off);
  }
  if ((t & 63) == 0) { rs1[t >> 6] = vs; rs2[t >> 6] = vq; }
  __syncthreads();
  float S1 = rs1[0] + rs1[1] + rs1[2] + rs1[3];
  float S2 = rs2[0] + rs2[1] + rs2[2] + rs2[3];
  float mu = S1 * (1.f/HDIM);
  float var = S2 * (1.f/HDIM) - mu * mu;
  float y = (val - mu) * rsqrtf(var + 1e-5f);
  y = fmaf(y, lngl[c], lnbl[c]);
  float h_new = fmaxf(y, 0.f);
  h_out[(size_t)n*HDIM + c] = h_new;
  _Float16 hh16 = (_Float16)h_new;
  h16[t] = *(unsigned short*)&hh16;
  __syncthreads();

  // fused next-op GEMM: out-channel t of xl/xr for the next layer / pair head
  int nt = t >> 4, nl = t & 15;
  const fp16v2* h2 = (const fp16v2*)h16;
  float accA = 0.f, accB = 0.f;
#pragma unroll
  for (int ccc = 0; ccc < 8; ++ccc) {
#pragma unroll
    for (int q = 0; q < 4; ++q) {
      size_t fo = (size_t)(nt*8 + ccc)*512 + (q*16 + nl)*8;
      union H8 wa, wb;
      wa.v8 = *(const f16x8*)(WhA + fo);
      wb.v8 = *(const f16x8*)(WhB + fo);
      int hb2 = ccc*16 + q*4;
#pragma unroll
      for (int p = 0; p < 4; ++p) {
        accA = FDOT2(wa.v2[p], h2[hb2 + p], accA);
        accB = FDOT2(wb.v2[p], h2[hb2 + p], accB);
      }
    }
  }
  float xlv = accA + bA[t];
  float xrv = accB + (bB ? bB[t] : 0.f);
  _Float16 ga16 = (_Float16)xlv, gb16 = (_Float16)xrv;
  xl_out[(size_t)n*HDIM + t] = *(unsigned short*)&ga16;
  xr_out[(size_t)n*HDIM + t] = *(unsigned short*)&gb16;
}

// ---------------- pair MLP via MFMA + value head (block 1056) ----------------
__global__ __launch_bounds__(256, 4) void pairval_k(
    const unsigned short* __restrict__ Ah, const unsigned short* __restrict__ Bh,
    const unsigned short* __restrict__ W2h,
    const float* __restrict__ b2, const float* __restrict__ W3,
    const float* __restrict__ b3,
    const float* __restrict__ h3, const float* __restrict__ v1W,
    const float* __restrict__ v1b, const float* __restrict__ v2W,
    const float* __restrict__ v2b,
    float* __restrict__ out, int N) {
  __shared__ float vrepr[512];
  __shared__ float vwsum[4];
  int bb = blockIdx.x;
  int t = threadIdx.x;
  size_t P = (size_t)N*(N-1)/2;

  if (bb == 1056) {
    // ---- value head solo: pool + 2-layer MLP ----
    float s = 0.f, m = -1e30f;
    for (int nn = 0; nn < N; ++nn) {
      float v = h3[(size_t)nn*HDIM + t];
      s += v; m = fmaxf(m, v);
    }
    vrepr[t] = s / (float)N;
    vrepr[256 + t] = m;
    __syncthreads();
    float p = 0.f;
#pragma unroll 8
    for (int k = 0; k < 512; ++k)
      p = fmaf(vrepr[k], v1W[(size_t)k*HDIM + t], p);
    float a = fmaxf(p + v1b[t], 0.f);
    float pd = a * v2W[t];
#pragma unroll
    for (int off = 1; off < 64; off <<= 1) pd += __shfl_xor(pd, off);
    if ((t & 63) == 0) vwsum[t >> 6] = pd;
    __syncthreads();
    if (t == 0) out[P] = vwsum[0] + vwsum[1] + vwsum[2] + vwsum[3] + v2b[0];
    return;
  }

  int half = bb & 1;
  int b = bb >> 1, ti = 0, rem = 32;
  while (b >= rem) { b -= rem; ti++; rem--; }
  int tj = ti + b;
  int i0 = ti * 16 + half * 8;
  int j0 = tj * 16;

  int w = t >> 6, l = t & 63;
  int quad = l >> 4, nl = l & 15;

  float b2v[8], w3v[8];
#pragma unroll
  for (int nt = 0; nt < 8; ++nt) {
    b2v[nt] = b2[nt*16 + nl];
    w3v[nt] = W3[nt*16 + nl];
  }

  const unsigned short* Brow = Bh + (size_t)(j0 + nl) * HDIM;
  const unsigned short* Arow0 = Ah + (size_t)(i0 + w*2) * HDIM;
  const f16x8 zv = {};

  f32x4 acc[2][8];
#pragma unroll
  for (int a2 = 0; a2 < 2; ++a2)
#pragma unroll
    for (int nt = 0; nt < 8; ++nt) acc[a2][nt] = (f32x4){0.f,0.f,0.f,0.f};

  for (int c = 0; c < 8; ++c) {
    int kb = c*32 + quad*8;
    f16x8 bv = *(const f16x8*)(Brow + kb);

    f16x8 afrag[2];
#pragma unroll
    for (int a2 = 0; a2 < 2; ++a2) {
      f16x8 av = *(const f16x8*)(Arow0 + (size_t)a2*HDIM + kb);
      afrag[a2] = __builtin_elementwise_max(av + bv, zv);
    }

#pragma unroll
    for (int nt = 0; nt < 8; ++nt) {
      f16x8 bfrag = *(const f16x8*)(W2h + (size_t)(((c*8 + nt)*64 + l) * 8));
#pragma unroll
      for (int a2 = 0; a2 < 2; ++a2)
        acc[a2][nt] = __builtin_amdgcn_mfma_f32_16x16x32_f16(
            afrag[a2], bfrag, acc[a2][nt], 0, 0, 0);
    }
  }

  float b3v = b3[0];
#pragma unroll
  for (int a2 = 0; a2 < 2; ++a2) {
    int i = i0 + w*2 + a2;
#pragma unroll
    for (int r = 0; r < 4; ++r) {
      float s = 0.f;
#pragma unroll
      for (int nt = 0; nt < 8; ++nt)
        s = fmaf(fmaxf(acc[a2][nt][r] + b2v[nt], 0.f), w3v[nt], s);
      s += __shfl_xor(s, 1);
      s += __shfl_xor(s, 2);
      s += __shfl_xor(s, 4);
      s += __shfl_xor(s, 8);
      if (nl == 0) {
        int j = j0 + quad*4 + r;
        if (i < j)
          out[(size_t)i*(2*N - i - 1)/2 + (j - i - 1)] = s + b3v;
      }
    }
  }
}

// ---------------- host orchestration ----------------
extern "C" void kernel_launch(void* const* d_in, const int* in_sizes, int n_in,
                              void* d_out, int out_size, void* d_ws, size_t ws_size,
                              hipStream_t stream) {
  const float* x    = (const float*)d_in[0];
  const int*   ei   = (const int*)  d_in[1];
  const float* ea   = (const float*)d_in[2];
  const float* embW = (const float*)d_in[3];
  const float* embb = (const float*)d_in[4];
  const float* Wl   = (const float*)d_in[5];
  const float* bl   = (const float*)d_in[6];
  const float* Wr   = (const float*)d_in[7];
  const float* br   = (const float*)d_in[8];
  const float* We   = (const float*)d_in[9];
  const float* att  = (const float*)d_in[10];
  const float* gb   = (const float*)d_in[11];
  const float* lng  = (const float*)d_in[12];
  const float* lnb  = (const float*)d_in[13];
  const float* p1W  = (const float*)d_in[14];
  const float* p1b  = (const float*)d_in[15];
  const float* p2W  = (const float*)d_in[16];
  const float* p2b  = (const float*)d_in[17];
  const float* p3W  = (const float*)d_in[18];
  const float* p3b  = (const float*)d_in[19];
  const float* v1W  = (const float*)d_in[20];
  const float* v1b  = (const float*)d_in[21];
  const float* v2W  = (const float*)d_in[22];
  const float* v2b  = (const float*)d_in[23];
  const float* coup = (const float*)d_in[24];

  int N = in_sizes[0];         // 512
  int E = in_sizes[2] / 3;     // 260000
  float* out = (float*)d_out;
  size_t P = (size_t)N*(N-1)/2;

  // ---- workspace carve ----
  char* w = (char*)d_ws;
  int*    rcnt = (int*)   (w + 0);         // 2048 (zeroed)
  float*  asum = (float*) (w + 2048);      // 6144 (zeroed)
  int*    dcol = (int*)   (w + 8192);      // 4096 (zeroed) -> 12288
  float*  ul   = (float*) (w + 12544);     // 1024
  float*  vl   = (float*) (w + 13568);     // 1024
  float*  ur   = (float*) (w + 14592);     // 1024
  float*  vr   = (float*) (w + 15616);     // 1024 -> 16640
  float*  pm   = (float*) (w + 16640);     // N*SEG*8*4 = 65536 -> 82176
  float*  pl   = (float*) (w + 82176);     // 65536 -> 147712
  float*  pacc = (float*) (w + 147712);    // N*SEG*256*4 = 2097152 -> 2244864
  float4* csr  = (float4*)(w + 2244864);   // 512*768*16 = 6291456 -> 8536320
  float*  hA   = (float*) (w + 8536320);   // 524288 -> 9060608
  float*  hB   = (float*) (w + 9060608);   // 524288 -> 9584896
  float*  h3   = (float*) (w + 9584896);   // 524288 -> 10109184
  unsigned short* xlA = (unsigned short*)(w + 10109184); // 262144 -> 10371328
  unsigned short* xrA = (unsigned short*)(w + 10371328); // 262144 -> 10633472
  unsigned short* xlB = (unsigned short*)(w + 10633472); // 262144 -> 10895616
  unsigned short* xrB = (unsigned short*)(w + 10895616); // 262144 -> 11157760
  unsigned short* Abh = (unsigned short*)(w + 11157760); // 262144 -> 11419904
  unsigned short* Bbh = (unsigned short*)(w + 11419904); // 262144 -> 11682048
  unsigned short* W2h = (unsigned short*)(w + 11682048); // 65536 -> 11747584
  unsigned short* Whall = (unsigned short*)(w + 11747584); // 1310720 -> 13058304

  int WB = (E + 1023) >> 10;

  zero_k<<<12, 256, 0, stream>>>((int*)w);           // rcnt+asum+dcol
  prep_k<<<WB + 672 + 2, 256, 0, stream>>>(
      ei, ea, E, Wl, Wr, p1W, p2W, embW, embb, bl, br,
      rcnt, asum, dcol, csr, Whall, W2h, ul, vl, ur, vr);

  // layer 0
  gat0_k<<<N*SEG, 256, 0, stream>>>(
      x, ul, vl, ur, vr, csr, rcnt, asum, We, att, pm, pl, pacc, N);
  mrg_k<<<N, 256, 0, stream>>>(
      pm, pl, pacc, (const float*)nullptr, x, embW, embb,
      gb, lng, lnb,
      Whall + (size_t)1*65536, Whall + (size_t)5*65536,
      bl + HDIM, br + HDIM,
      hA, xlA, xrA, dcol, coup, out + P + 1, N);

  // layer 1
  gat_k<<<N*SEG, 256, 0, stream>>>(
      xlA, xrA, csr, rcnt, asum,
      We + (size_t)1*3*HDIM, att + (size_t)1*HDIM, pm, pl, pacc, N);
  mrg_k<<<N, 256, 0, stream>>>(
      pm, pl, pacc, hA, x, embW, embb,
      gb + HDIM, lng + HDIM, lnb + HDIM,
      Whall + (size_t)2*65536, Whall + (size_t)6*65536,
      bl + 2*HDIM, br + 2*HDIM,
      hB, xlB, xrB, (const int*)nullptr, coup, (float*)nullptr, N);

  // layer 2
  gat_k<<<N*SEG, 256, 0, stream>>>(
      xlB, xrB, csr, rcnt, asum,
      We + (size_t)2*3*HDIM, att + (size_t)2*HDIM, pm, pl, pacc, N);
  mrg_k<<<N, 256, 0, stream>>>(
      pm, pl, pacc, hB, x, embW, embb,
      gb + 2*HDIM, lng + 2*HDIM, lnb + 2*HDIM,
      Whall + (size_t)3*65536, Whall + (size_t)7*65536,
      bl + 3*HDIM, br + 3*HDIM,
      hA, xlA, xrA, (const int*)nullptr, coup, (float*)nullptr, N);

  // layer 3 (GEMM -> pair head A/B)
  gat_k<<<N*SEG, 256, 0, stream>>>(
      xlA, xrA, csr, rcnt, asum,
      We + (size_t)3*3*HDIM, att + (size_t)3*HDIM, pm, pl, pacc, N);
  mrg_k<<<N, 256, 0, stream>>>(
      pm, pl, pacc, hA, x, embW, embb,
      gb + 3*HDIM, lng + 3*HDIM, lnb + 3*HDIM,
      Whall + (size_t)8*65536, Whall + (size_t)9*65536,
      p1b, (const float*)nullptr,
      h3, Abh, Bbh, (const int*)nullptr, coup, (float*)nullptr, N);

  // pair MLP (1056 blocks) + value head (block 1056), concurrent
  pairval_k<<<1057, 256, 0, stream>>>(
      Abh, Bbh, W2h, p2b, p3W, p3b, h3, v1W, v1b, v2W, v2b, out, N);
}